// Round 1
// baseline (726.016 us; speedup 1.0000x reference)
//
#include <hip/hip_runtime.h>
#include <hip/hip_bf16.h>
#include <stdint.h>

#define T_LEN 4096
#define B_SZ  8
#define D_IN  1024
#define D_M   256
#define N_C   157

typedef __attribute__((ext_vector_type(8))) short short8;
typedef __attribute__((ext_vector_type(4))) float floatx4;

static __device__ __forceinline__ unsigned short f2bf(float f) {
  unsigned u = __float_as_uint(f);
  u += 0x7FFFu + ((u >> 16) & 1u);
  return (unsigned short)(u >> 16);
}
static __device__ __forceinline__ float bf2f(unsigned short h) {
  return __uint_as_float(((unsigned)h) << 16);
}

// ---------------- weight prep: fp32 -> bf16, 22 segments in one launch ----
struct WSeg { const float* src; int n; int off; };
struct WPrepArgs { WSeg seg[22]; };

__global__ void wprep_kernel(WPrepArgs a, unsigned short* __restrict__ wbuf) {
  WSeg s = a.seg[blockIdx.x];
  for (int i = (blockIdx.y << 8) + threadIdx.x; i < s.n; i += (gridDim.y << 8))
    wbuf[s.off + i] = f2bf(s.src[i]);
}

// ---------------- x (B,DIN,T) f32 -> xT (B,T,DIN) bf16 --------------------
__global__ void transpose_xT(const float* __restrict__ x,
                             unsigned short* __restrict__ xT) {
  __shared__ float tile[64][65];
  const int t0 = blockIdx.x << 6;
  const int i0 = blockIdx.y << 6;
  const int b  = blockIdx.z;
  const int tid = threadIdx.x;
  {
    const int row = tid >> 2;
    const int cc  = (tid & 3) << 4;
    const float* src = x + ((size_t)b * D_IN + (i0 + row)) * T_LEN + t0 + cc;
#pragma unroll
    for (int p = 0; p < 4; ++p) {
      float4 v = *(const float4*)(src + p * 4);
      tile[row][cc + p * 4 + 0] = v.x;
      tile[row][cc + p * 4 + 1] = v.y;
      tile[row][cc + p * 4 + 2] = v.z;
      tile[row][cc + p * 4 + 3] = v.w;
    }
  }
  __syncthreads();
#pragma unroll
  for (int it = 0; it < 2; ++it) {
    const int task = tid + (it << 8);
    const int tr = task >> 3;
    const int ic = (task & 7) << 3;
    short8 o;
#pragma unroll
    for (int j = 0; j < 8; ++j) o[j] = (short)f2bf(tile[ic + j][tr]);
    *(short8*)(xT + ((size_t)b * T_LEN + (t0 + tr)) * D_IN + i0 + ic) = o;
  }
}

// ---------------- MFMA GEMM: C(B,T,Mw) = Xact(B,T,K) * W(Mw,K)^T ----------
// A-frag: A[m=lane&15][k=(lane>>4)*8+j]  B-frag: B[k][n=lane&15]
// C/D: col=lane&15, row=(lane>>4)*4+reg   (16x16x32 bf16, m89-verified)
template<bool HAS_BIAS, bool HAS_RES, bool HAS_MASK, bool WRITE_F32,
         bool WRITE_BF16, bool OUT_CT>
__global__ __launch_bounds__(256)
void gemm_kernel(const unsigned short* __restrict__ Xact,
                 const unsigned short* __restrict__ W,
                 const float* __restrict__ bias,
                 const float* __restrict__ resid,
                 const float* __restrict__ mask,
                 float* __restrict__ outF,
                 unsigned short* __restrict__ outB,
                 int K, int Mw) {
  constexpr int LDS_LD = 72;  // +8 bf16 pad: 144B rows, keeps 16B align, 4-bank row shift
  __shared__ unsigned short sA[128 * LDS_LD];
  __shared__ unsigned short sB[128 * LDS_LD];

  const int t0 = blockIdx.x << 7;
  const int n0 = blockIdx.y << 7;
  const int b  = blockIdx.z;
  const int tid = threadIdx.x;
  const int wv   = tid >> 6;
  const int lane = tid & 63;
  const int wm = (wv >> 1) << 6;
  const int wn = (wv & 1) << 6;
  const int fm = lane & 15;
  const int fq = lane >> 4;

  const unsigned short* Xb = Xact + (size_t)b * T_LEN * (size_t)K;

  const floatx4 fz = {0.f, 0.f, 0.f, 0.f};
  floatx4 acc[4][4];
#pragma unroll
  for (int i = 0; i < 4; ++i)
#pragma unroll
    for (int j = 0; j < 4; ++j) acc[i][j] = fz;

  for (int kk = 0; kk < K; kk += 64) {
#pragma unroll
    for (int it = 0; it < 4; ++it) {
      int c = tid + (it << 8);
      int m = c >> 3;
      int ko = (c & 7) << 3;
      *(short8*)&sA[m * LDS_LD + ko] =
          *(const short8*)(Xb + (size_t)(t0 + m) * K + (kk + ko));
    }
#pragma unroll
    for (int it = 0; it < 4; ++it) {
      int c = tid + (it << 8);
      int n = c >> 3;
      int ko = (c & 7) << 3;
      short8 val = {0, 0, 0, 0, 0, 0, 0, 0};
      if (n0 + n < Mw)
        val = *(const short8*)(W + (size_t)(n0 + n) * K + (kk + ko));
      *(short8*)&sB[n * LDS_LD + ko] = val;
    }
    __syncthreads();
#pragma unroll
    for (int ks = 0; ks < 64; ks += 32) {
      short8 af[4], bfr[4];
#pragma unroll
      for (int i = 0; i < 4; ++i)
        af[i] = *(short8*)&sA[(wm + (i << 4) + fm) * LDS_LD + ks + (fq << 3)];
#pragma unroll
      for (int j = 0; j < 4; ++j)
        bfr[j] = *(short8*)&sB[(wn + (j << 4) + fm) * LDS_LD + ks + (fq << 3)];
#pragma unroll
      for (int i = 0; i < 4; ++i)
#pragma unroll
        for (int j = 0; j < 4; ++j)
          acc[i][j] = __builtin_amdgcn_mfma_f32_16x16x32_bf16(
              af[i], bfr[j], acc[i][j], 0, 0, 0);
    }
    __syncthreads();
  }

  // epilogue
#pragma unroll
  for (int i = 0; i < 4; ++i) {
#pragma unroll
    for (int j = 0; j < 4; ++j) {
      const int co = n0 + wn + (j << 4) + fm;
      if (co >= Mw) continue;
      const float bi = HAS_BIAS ? bias[co] : 0.0f;
#pragma unroll
      for (int r = 0; r < 4; ++r) {
        const int t = t0 + wm + (i << 4) + (fq << 2) + r;
        float val = acc[i][j][r] + bi;
        const size_t idx = ((size_t)b * T_LEN + t) * (size_t)Mw + co;
        if (HAS_RES) val += resid[idx];
        if (HAS_MASK) val *= mask[(size_t)b * T_LEN + t];
        if (WRITE_F32) {
          if (OUT_CT)
            outF[(size_t)b * Mw * T_LEN + (size_t)co * T_LEN + t] = val;
          else
            outF[idx] = val;
        }
        if (WRITE_BF16) outB[idx] = f2bf(val);
      }
    }
  }
}

// ---------------- 3-tap dilated softmax attention + relu ------------------
// qkv (B,T,768) bf16: [0:256)=q [256:512)=k [512:768)=v  ->  h (B,T,256) bf16
__global__ void attn_kernel(const unsigned short* __restrict__ qkv,
                            unsigned short* __restrict__ hbuf, int d) {
  const int tid = threadIdx.x;
  const int t = (blockIdx.x << 3) + (tid >> 5);
  const int b = blockIdx.y;
  const int c8 = (tid & 31) << 3;
  const unsigned short* base = qkv + ((size_t)b * T_LEN + t) * 768;
  const short8 z8 = {0, 0, 0, 0, 0, 0, 0, 0};
  short8 qv = *(const short8*)(base + c8);
  short8 kc = *(const short8*)(base + 256 + c8);
  short8 vc = *(const short8*)(base + 512 + c8);
  short8 km = z8, kp = z8, vm = z8, vp = z8;
  const long off = (long)d * 768;
  if (t >= d) {
    km = *(const short8*)(base - off + 256 + c8);
    vm = *(const short8*)(base - off + 512 + c8);
  }
  if (t + d < T_LEN) {
    kp = *(const short8*)(base + off + 256 + c8);
    vp = *(const short8*)(base + off + 512 + c8);
  }
  short8 o;
#pragma unroll
  for (int e = 0; e < 8; ++e) {
    float q  = bf2f((unsigned short)qv[e]);
    float s0 = q * bf2f((unsigned short)km[e]);
    float s1 = q * bf2f((unsigned short)kc[e]);
    float s2 = q * bf2f((unsigned short)kp[e]);
    float mx = fmaxf(s0, fmaxf(s1, s2));
    float e0 = __expf(s0 - mx), e1 = __expf(s1 - mx), e2 = __expf(s2 - mx);
    float num = e0 * bf2f((unsigned short)vm[e]) +
                e1 * bf2f((unsigned short)vc[e]) +
                e2 * bf2f((unsigned short)vp[e]);
    float r = num / (e0 + e1 + e2);
    o[e] = (short)f2bf(fmaxf(r, 0.0f));
  }
  *(short8*)(hbuf + ((size_t)b * T_LEN + t) * D_M + c8) = o;
}

// ---------------- launch ---------------------------------------------------
extern "C" void kernel_launch(void* const* d_in, const int* in_sizes, int n_in,
                              void* d_out, int out_size, void* d_ws, size_t ws_size,
                              hipStream_t stream) {
  const float* x    = (const float*)d_in[0];
  const float* mask = (const float*)d_in[1];

  char* ws = (char*)d_ws;
  unsigned short* xT   = (unsigned short*)ws;                      // 67108864 B
  unsigned short* qkv  = xT;                                       // alias (xT dead after gemm0)
  float*          outF = (float*)(ws + 67108864);                  // 33554432 B
  unsigned short* outB = (unsigned short*)(ws + 100663296);        // 16777216 B
  unsigned short* hbuf = (unsigned short*)(ws + 117440512);        // 16777216 B
  unsigned short* wbuf = (unsigned short*)(ws + 134217728);        // ~3.2 MB

  const int WB0  = 0;        // 256x1024
  const int WQKV = 262144;   // 5 x 768x256 stacked [wq;wk;wv]
  const int WBT  = 1245184;  // 5 x 256x256
  const int WB6  = 1572864;  // 157x256

  WPrepArgs pa;
  int si = 0;
  pa.seg[si++] = { (const float*)d_in[2], 262144, WB0 };
  for (int l = 0; l < 5; ++l) {
    int bi = 4 + l * 5;
    pa.seg[si++] = { (const float*)d_in[bi + 0], 65536, WQKV + l * 196608 };
    pa.seg[si++] = { (const float*)d_in[bi + 1], 65536, WQKV + l * 196608 + 65536 };
    pa.seg[si++] = { (const float*)d_in[bi + 2], 65536, WQKV + l * 196608 + 131072 };
    pa.seg[si++] = { (const float*)d_in[bi + 3], 65536, WBT + l * 65536 };
  }
  pa.seg[si++] = { (const float*)d_in[29], 40192, WB6 };

  wprep_kernel<<<dim3(22, 64), 256, 0, stream>>>(pa, wbuf);
  transpose_xT<<<dim3(64, 16, 8), 256, 0, stream>>>(x, xT);

  // bottle0: out = w0 @ x + b0   (fp32 + bf16 writes)
  gemm_kernel<true, false, false, true, true, false>
      <<<dim3(32, 2, 8), 256, 0, stream>>>(
          xT, wbuf + WB0, (const float*)d_in[3], nullptr, mask,
          outF, outB, 1024, 256);

  const int dils[5] = {1, 2, 4, 8, 16};
  for (int l = 0; l < 5; ++l) {
    int bi = 4 + l * 5;
    // qkv = [wq;wk;wv] @ out  (bf16 write only)
    gemm_kernel<false, false, false, false, true, false>
        <<<dim3(32, 6, 8), 256, 0, stream>>>(
            outB, wbuf + WQKV + l * 196608, nullptr, nullptr, mask,
            nullptr, qkv, 256, 768);
    attn_kernel<<<dim3(512, 8), 256, 0, stream>>>(qkv, hbuf, dils[l]);
    // out = (out + bw @ h + bb) * mask   (fp32 + bf16 writes, in-place resid)
    gemm_kernel<true, true, true, true, true, false>
        <<<dim3(32, 2, 8), 256, 0, stream>>>(
            hbuf, wbuf + WBT + l * 65536, (const float*)d_in[bi + 4], outF, mask,
            outF, outB, 256, 256);
  }

  // final: d_out(B,157,T) = (w6 @ out + b6) * mask  (channel-major store)
  gemm_kernel<true, false, true, true, false, true>
      <<<dim3(32, 2, 8), 256, 0, stream>>>(
          outB, wbuf + WB6, (const float*)d_in[30], nullptr, mask,
          (float*)d_out, nullptr, 256, 157);
}

// Round 2
// 723.186 us; speedup vs baseline: 1.0039x; 1.0039x over previous
//
#include <hip/hip_runtime.h>
#include <hip/hip_bf16.h>
#include <stdint.h>

#define T_LEN 4096
#define B_SZ  8
#define D_IN  1024
#define D_M   256
#define N_C   157

typedef __attribute__((ext_vector_type(8))) short short8;
typedef __attribute__((ext_vector_type(4))) float floatx4;

static __device__ __forceinline__ unsigned short f2bf(float f) {
  unsigned u = __float_as_uint(f);
  u += 0x7FFFu + ((u >> 16) & 1u);
  return (unsigned short)(u >> 16);
}
static __device__ __forceinline__ float bf2f(unsigned short h) {
  return __uint_as_float(((unsigned)h) << 16);
}

// ---------------- weight prep: fp32 -> bf16, 22 segments in one launch ----
struct WSeg { const float* src; int n; int off; };
struct WPrepArgs { WSeg seg[22]; };

__global__ void wprep_kernel(WPrepArgs a, unsigned short* __restrict__ wbuf) {
  WSeg s = a.seg[blockIdx.x];
  for (int i = (blockIdx.y << 8) + threadIdx.x; i < s.n; i += (gridDim.y << 8))
    wbuf[s.off + i] = f2bf(s.src[i]);
}

// ---------------- x (B,DIN,T) f32 -> xT (B,T,DIN) bf16 --------------------
__global__ void transpose_xT(const float* __restrict__ x,
                             unsigned short* __restrict__ xT) {
  __shared__ float tile[64][65];
  const int t0 = blockIdx.x << 6;
  const int i0 = blockIdx.y << 6;
  const int b  = blockIdx.z;
  const int tid = threadIdx.x;
  {
    const int row = tid >> 2;
    const int cc  = (tid & 3) << 4;
    const float* src = x + ((size_t)b * D_IN + (i0 + row)) * T_LEN + t0 + cc;
#pragma unroll
    for (int p = 0; p < 4; ++p) {
      float4 v = *(const float4*)(src + p * 4);
      tile[row][cc + p * 4 + 0] = v.x;
      tile[row][cc + p * 4 + 1] = v.y;
      tile[row][cc + p * 4 + 2] = v.z;
      tile[row][cc + p * 4 + 3] = v.w;
    }
  }
  __syncthreads();
#pragma unroll
  for (int it = 0; it < 2; ++it) {
    const int task = tid + (it << 8);
    const int tr = task >> 3;
    const int ic = (task & 7) << 3;
    short8 o;
#pragma unroll
    for (int j = 0; j < 8; ++j) o[j] = (short)f2bf(tile[ic + j][tr]);
    *(short8*)(xT + ((size_t)b * T_LEN + (t0 + tr)) * D_IN + i0 + ic) = o;
  }
}

// ---------------- MFMA GEMM: C(B,T,Mw) = A(B,T,K) * W(Mw,K)^T -------------
// ATTN variant: A rows are computed on the fly from qkv (B,T,768):
//   a[t][c] = relu( softmax3(q*k_{-d},q*k_0,q*k_{+d}) . v )
// A-frag: A[m=lane&15][k=(lane>>4)*8+j]  B-frag: B[k][n=lane&15]
// C/D: col=lane&15, row=(lane>>4)*4+reg   (16x16x32 bf16, m89-verified)
template<bool ATTN, bool HAS_BIAS, bool HAS_RES, bool HAS_MASK,
         bool WRITE_BF16, bool OUT_CT_F32>
__global__ __launch_bounds__(256)
void gemm_kernel(const unsigned short* __restrict__ Xact,
                 const unsigned short* __restrict__ W,
                 const float* __restrict__ bias,
                 const unsigned short* __restrict__ residB,
                 const float* __restrict__ mask,
                 float* __restrict__ outF,
                 unsigned short* __restrict__ outB,
                 int K, int Mw, int dil) {
  constexpr int LDS_LD = 72;  // +8 bf16 pad
  __shared__ unsigned short sA[128 * LDS_LD];
  __shared__ unsigned short sB[128 * LDS_LD];

  const int n0 = blockIdx.x << 7;
  const int t0 = blockIdx.y << 7;
  const int b  = blockIdx.z;
  const int tid = threadIdx.x;
  const int wv   = tid >> 6;
  const int lane = tid & 63;
  const int wm = (wv >> 1) << 6;
  const int wn = (wv & 1) << 6;
  const int fm = lane & 15;
  const int fq = lane >> 4;

  const unsigned short* Xb =
      Xact + (size_t)b * T_LEN * (size_t)(ATTN ? 768 : K);

  const short8 z8 = {0, 0, 0, 0, 0, 0, 0, 0};
  const floatx4 fz = {0.f, 0.f, 0.f, 0.f};
  floatx4 acc[4][4];
#pragma unroll
  for (int i = 0; i < 4; ++i)
#pragma unroll
    for (int j = 0; j < 4; ++j) acc[i][j] = fz;

  for (int kk = 0; kk < K; kk += 64) {
    if constexpr (ATTN) {
#pragma unroll
      for (int it = 0; it < 4; ++it) {
        int c = tid + (it << 8);
        int m = c >> 3;
        int ch = kk + ((c & 7) << 3);
        int t = t0 + m;
        const unsigned short* base = Xb + (size_t)t * 768 + ch;
        short8 qv = *(const short8*)(base);
        short8 kc = *(const short8*)(base + 256);
        short8 vc = *(const short8*)(base + 512);
        short8 km = z8, kp = z8, vm = z8, vp = z8;
        const long off = (long)dil * 768;
        if (t >= dil) {
          km = *(const short8*)(base - off + 256);
          vm = *(const short8*)(base - off + 512);
        }
        if (t + dil < T_LEN) {
          kp = *(const short8*)(base + off + 256);
          vp = *(const short8*)(base + off + 512);
        }
        short8 o;
#pragma unroll
        for (int e = 0; e < 8; ++e) {
          float q  = bf2f((unsigned short)qv[e]);
          float s0 = q * bf2f((unsigned short)km[e]);
          float s1 = q * bf2f((unsigned short)kc[e]);
          float s2 = q * bf2f((unsigned short)kp[e]);
          float mx = fmaxf(s0, fmaxf(s1, s2));
          float e0 = __expf(s0 - mx), e1 = __expf(s1 - mx), e2 = __expf(s2 - mx);
          float num = e0 * bf2f((unsigned short)vm[e]) +
                      e1 * bf2f((unsigned short)vc[e]) +
                      e2 * bf2f((unsigned short)vp[e]);
          float r = num / (e0 + e1 + e2);
          o[e] = (short)f2bf(fmaxf(r, 0.0f));
        }
        *(short8*)&sA[m * LDS_LD + (ch - kk)] = o;
      }
    } else {
#pragma unroll
      for (int it = 0; it < 4; ++it) {
        int c = tid + (it << 8);
        int m = c >> 3;
        int ko = (c & 7) << 3;
        *(short8*)&sA[m * LDS_LD + ko] =
            *(const short8*)(Xb + (size_t)(t0 + m) * K + (kk + ko));
      }
    }
#pragma unroll
    for (int it = 0; it < 4; ++it) {
      int c = tid + (it << 8);
      int n = c >> 3;
      int ko = (c & 7) << 3;
      short8 val = z8;
      if (n0 + n < Mw)
        val = *(const short8*)(W + (size_t)(n0 + n) * K + (kk + ko));
      *(short8*)&sB[n * LDS_LD + ko] = val;
    }
    __syncthreads();
#pragma unroll
    for (int ks = 0; ks < 64; ks += 32) {
      short8 af[4], bfr[4];
#pragma unroll
      for (int i = 0; i < 4; ++i)
        af[i] = *(short8*)&sA[(wm + (i << 4) + fm) * LDS_LD + ks + (fq << 3)];
#pragma unroll
      for (int j = 0; j < 4; ++j)
        bfr[j] = *(short8*)&sB[(wn + (j << 4) + fm) * LDS_LD + ks + (fq << 3)];
#pragma unroll
      for (int i = 0; i < 4; ++i)
#pragma unroll
        for (int j = 0; j < 4; ++j)
          acc[i][j] = __builtin_amdgcn_mfma_f32_16x16x32_bf16(
              af[i], bfr[j], acc[i][j], 0, 0, 0);
    }
    __syncthreads();
  }

  // epilogue
#pragma unroll
  for (int i = 0; i < 4; ++i) {
#pragma unroll
    for (int j = 0; j < 4; ++j) {
      const int co = n0 + wn + (j << 4) + fm;
      if (co >= Mw) continue;
      const float bi = HAS_BIAS ? bias[co] : 0.0f;
#pragma unroll
      for (int r = 0; r < 4; ++r) {
        const int t = t0 + wm + (i << 4) + (fq << 2) + r;
        float val = acc[i][j][r] + bi;
        const size_t idx = ((size_t)b * T_LEN + t) * (size_t)Mw + co;
        if (HAS_RES) val += bf2f(residB[idx]);
        if (HAS_MASK) val *= mask[(size_t)b * T_LEN + t];
        if (OUT_CT_F32)
          outF[(size_t)b * Mw * T_LEN + (size_t)co * T_LEN + t] = val;
        if (WRITE_BF16) outB[idx] = f2bf(val);
      }
    }
  }
}

// ---------------- launch ---------------------------------------------------
extern "C" void kernel_launch(void* const* d_in, const int* in_sizes, int n_in,
                              void* d_out, int out_size, void* d_ws, size_t ws_size,
                              hipStream_t stream) {
  const float* x    = (const float*)d_in[0];
  const float* mask = (const float*)d_in[1];

  char* ws = (char*)d_ws;
  unsigned short* xT   = (unsigned short*)ws;                 // 67108864 B
  unsigned short* qkv  = xT;                                  // alias (xT dead after gemm0)
  unsigned short* outB = (unsigned short*)(ws + 67108864);    // 16777216 B
  unsigned short* wbuf = (unsigned short*)(ws + 83886080);    // ~3.2 MB

  const int WB0  = 0;        // 256x1024
  const int WQKV = 262144;   // 5 x 768x256 stacked [wq;wk;wv]
  const int WBT  = 1245184;  // 5 x 256x256
  const int WB6  = 1572864;  // 157x256

  WPrepArgs pa;
  int si = 0;
  pa.seg[si++] = { (const float*)d_in[2], 262144, WB0 };
  for (int l = 0; l < 5; ++l) {
    int bi = 4 + l * 5;
    pa.seg[si++] = { (const float*)d_in[bi + 0], 65536, WQKV + l * 196608 };
    pa.seg[si++] = { (const float*)d_in[bi + 1], 65536, WQKV + l * 196608 + 65536 };
    pa.seg[si++] = { (const float*)d_in[bi + 2], 65536, WQKV + l * 196608 + 131072 };
    pa.seg[si++] = { (const float*)d_in[bi + 3], 65536, WBT + l * 65536 };
  }
  pa.seg[si++] = { (const float*)d_in[29], 40192, WB6 };

  wprep_kernel<<<dim3(22, 64), 256, 0, stream>>>(pa, wbuf);
  transpose_xT<<<dim3(64, 16, 8), 256, 0, stream>>>(x, xT);

  // bottle0: out = w0 @ x + b0  (bf16)
  gemm_kernel<false, true, false, false, true, false>
      <<<dim3(2, 32, 8), 256, 0, stream>>>(
          xT, wbuf + WB0, (const float*)d_in[3], nullptr, mask,
          nullptr, outB, 1024, 256, 0);

  const int dils[5] = {1, 2, 4, 8, 16};
  for (int l = 0; l < 5; ++l) {
    int bi = 4 + l * 5;
    // qkv = [wq;wk;wv] @ out  (bf16)
    gemm_kernel<false, false, false, false, true, false>
        <<<dim3(6, 32, 8), 256, 0, stream>>>(
            outB, wbuf + WQKV + l * 196608, nullptr, nullptr, mask,
            nullptr, qkv, 256, 768, 0);
    // out = (out + bw @ relu(attn(qkv)) + bb) * mask   (attn fused in A-staging)
    gemm_kernel<true, true, true, true, true, false>
        <<<dim3(2, 32, 8), 256, 0, stream>>>(
            qkv, wbuf + WBT + l * 65536, (const float*)d_in[bi + 4], outB, mask,
            nullptr, outB, 256, 256, dils[l]);
  }

  // final: d_out(B,157,T) = (w6 @ out + b6) * mask  (channel-major f32 store)
  gemm_kernel<false, true, false, true, false, true>
      <<<dim3(2, 32, 8), 256, 0, stream>>>(
          outB, wbuf + WB6, (const float*)d_in[30], nullptr, mask,
          (float*)d_out, nullptr, 256, 157, 0);
}

// Round 3
// 674.555 us; speedup vs baseline: 1.0763x; 1.0721x over previous
//
#include <hip/hip_runtime.h>
#include <hip/hip_bf16.h>
#include <stdint.h>

#define T_LEN 4096
#define B_SZ  8
#define D_IN  1024
#define D_M   256
#define N_C   157

typedef __attribute__((ext_vector_type(8))) short short8;
typedef __attribute__((ext_vector_type(4))) float floatx4;

static __device__ __forceinline__ unsigned short f2bf(float f) {
  unsigned u = __float_as_uint(f);
  u += 0x7FFFu + ((u >> 16) & 1u);
  return (unsigned short)(u >> 16);
}
static __device__ __forceinline__ float bf2f(unsigned short h) {
  return __uint_as_float(((unsigned)h) << 16);
}

// async global->LDS, 16B per lane; LDS dest = wave-uniform base + lane*16
static __device__ __forceinline__ void gl_lds16(const unsigned short* g,
                                                unsigned short* l) {
  __builtin_amdgcn_global_load_lds(
      (const __attribute__((address_space(1))) unsigned int*)g,
      (__attribute__((address_space(3))) unsigned int*)l, 16, 0, 0);
}

// ---------------- weight prep: fp32 -> bf16, 22 segments in one launch ----
struct WSeg { const float* src; int n; int off; };
struct WPrepArgs { WSeg seg[22]; };

__global__ void wprep_kernel(WPrepArgs a, unsigned short* __restrict__ wbuf) {
  WSeg s = a.seg[blockIdx.x];
  for (int i = (blockIdx.y << 8) + threadIdx.x; i < s.n; i += (gridDim.y << 8))
    wbuf[s.off + i] = f2bf(s.src[i]);
}

// ---------------- x (B,DIN,T) f32 -> xT (B,T,DIN) bf16 --------------------
__global__ void transpose_xT(const float* __restrict__ x,
                             unsigned short* __restrict__ xT) {
  __shared__ float tile[64][65];
  const int t0 = blockIdx.x << 6;
  const int i0 = blockIdx.y << 6;
  const int b  = blockIdx.z;
  const int tid = threadIdx.x;
  {
    const int row = tid >> 2;
    const int cc  = (tid & 3) << 4;
    const float* src = x + ((size_t)b * D_IN + (i0 + row)) * T_LEN + t0 + cc;
#pragma unroll
    for (int p = 0; p < 4; ++p) {
      float4 v = *(const float4*)(src + p * 4);
      tile[row][cc + p * 4 + 0] = v.x;
      tile[row][cc + p * 4 + 1] = v.y;
      tile[row][cc + p * 4 + 2] = v.z;
      tile[row][cc + p * 4 + 3] = v.w;
    }
  }
  __syncthreads();
#pragma unroll
  for (int it = 0; it < 2; ++it) {
    const int task = tid + (it << 8);
    const int tr = task >> 3;
    const int ic = (task & 7) << 3;
    short8 o;
#pragma unroll
    for (int j = 0; j < 8; ++j) o[j] = (short)f2bf(tile[ic + j][tr]);
    *(short8*)(xT + ((size_t)b * T_LEN + (t0 + tr)) * D_IN + i0 + ic) = o;
  }
}

// ---------------- MFMA GEMM: C(B,T,Mw) = A(B,T,K) * W(Mw,K)^T -------------
// LDS tiles: 128 rows x 64 bf16 cols (128B/row), XOR-swizzled 16B blocks:
//   element (row, k) lives at row*128B + ((k/8) ^ (row&7))*16B + (k%8)*2B
// -> global_load_lds lane-contiguous writes AND conflict-free ds_read_b128.
// A-frag: A[m=lane&15][k=(lane>>4)*8+j]  B-frag: B[k][n=lane&15]
// C/D: col=lane&15, row=(lane>>4)*4+reg   (16x16x32 bf16, m89-verified)
template<bool ATTN, bool HAS_BIAS, bool HAS_RES, bool HAS_MASK,
         bool WRITE_BF16, bool OUT_CT_F32>
__global__ __launch_bounds__(256)
void gemm_kernel(const unsigned short* __restrict__ Xact,
                 const unsigned short* __restrict__ W,
                 const float* __restrict__ bias,
                 const unsigned short* __restrict__ residB,
                 const float* __restrict__ mask,
                 float* __restrict__ outF,
                 unsigned short* __restrict__ outB,
                 int K, int Mw, int dil) {
  __shared__ unsigned short sA[128 * 64];
  __shared__ unsigned short sB[128 * 64];

  const int n0 = blockIdx.x << 7;
  const int t0 = blockIdx.y << 7;
  const int b  = blockIdx.z;
  const int tid = threadIdx.x;
  const int wv   = tid >> 6;
  const int lane = tid & 63;
  const int wm = (wv >> 1) << 6;
  const int wn = (wv & 1) << 6;
  const int fm = lane & 15;
  const int fq = lane >> 4;
  const int lrow = lane >> 3;                       // 0..7
  const int cbg8 = (((lane & 7) ^ lrow) << 3);      // swizzled src col (shorts)

  const unsigned short* Xb =
      Xact + (size_t)b * T_LEN * (size_t)(ATTN ? 768 : K);

  const short8 z8 = {0, 0, 0, 0, 0, 0, 0, 0};
  const floatx4 fz = {0.f, 0.f, 0.f, 0.f};
  floatx4 acc[4][4];
#pragma unroll
  for (int i = 0; i < 4; ++i)
#pragma unroll
    for (int j = 0; j < 4; ++j) acc[i][j] = fz;

  for (int kk = 0; kk < K; kk += 64) {
    if constexpr (ATTN) {
#pragma unroll
      for (int it = 0; it < 4; ++it) {
        int c = tid + (it << 8);
        int m = c >> 3;
        int cb = c & 7;
        int ch = kk + (cb << 3);
        int t = t0 + m;
        const unsigned short* base = Xb + (size_t)t * 768 + ch;
        short8 qv = *(const short8*)(base);
        short8 kc = *(const short8*)(base + 256);
        short8 vc = *(const short8*)(base + 512);
        short8 km = z8, kp = z8, vm = z8, vp = z8;
        const long off = (long)dil * 768;
        if (t >= dil) {
          km = *(const short8*)(base - off + 256);
          vm = *(const short8*)(base - off + 512);
        }
        if (t + dil < T_LEN) {
          kp = *(const short8*)(base + off + 256);
          vp = *(const short8*)(base + off + 512);
        }
        short8 o;
#pragma unroll
        for (int e = 0; e < 8; ++e) {
          float q  = bf2f((unsigned short)qv[e]);
          float s0 = q * bf2f((unsigned short)km[e]);
          float s1 = q * bf2f((unsigned short)kc[e]);
          float s2 = q * bf2f((unsigned short)kp[e]);
          float mx = fmaxf(s0, fmaxf(s1, s2));
          float e0 = __expf(s0 - mx), e1 = __expf(s1 - mx), e2 = __expf(s2 - mx);
          float num = e0 * bf2f((unsigned short)vm[e]) +
                      e1 * bf2f((unsigned short)vc[e]) +
                      e2 * bf2f((unsigned short)vp[e]);
          float r = num / (e0 + e1 + e2);
          o[e] = (short)f2bf(fmaxf(r, 0.0f));
        }
        *(short8*)&sA[(m << 6) + ((cb ^ (m & 7)) << 3)] = o;
      }
    } else {
#pragma unroll
      for (int p = 0; p < 4; ++p) {
        const int slot = (p << 2) + wv;             // 0..15 wave-pass
        gl_lds16(Xb + (size_t)(t0 + (slot << 3) + lrow) * K + kk + cbg8,
                 sA + slot * 512);
      }
    }
#pragma unroll
    for (int p = 0; p < 4; ++p) {
      const int slot = (p << 2) + wv;
      gl_lds16(W + (size_t)(n0 + (slot << 3) + lrow) * K + kk + cbg8,
               sB + slot * 512);
    }
    __syncthreads();
#pragma unroll
    for (int ks = 0; ks < 64; ks += 32) {
      const int cbase = ((fq + (ks >> 3)) ^ (fm & 7)) << 3;
      short8 af[4], bfr[4];
#pragma unroll
      for (int i = 0; i < 4; ++i)
        af[i] = *(short8*)&sA[((wm + (i << 4) + fm) << 6) + cbase];
#pragma unroll
      for (int j = 0; j < 4; ++j)
        bfr[j] = *(short8*)&sB[((wn + (j << 4) + fm) << 6) + cbase];
#pragma unroll
      for (int i = 0; i < 4; ++i)
#pragma unroll
        for (int j = 0; j < 4; ++j)
          acc[i][j] = __builtin_amdgcn_mfma_f32_16x16x32_bf16(
              af[i], bfr[j], acc[i][j], 0, 0, 0);
    }
    __syncthreads();
  }

  // epilogue
#pragma unroll
  for (int i = 0; i < 4; ++i) {
#pragma unroll
    for (int j = 0; j < 4; ++j) {
      const int co = n0 + wn + (j << 4) + fm;
      if (co >= Mw) continue;
      const float bi = HAS_BIAS ? bias[co] : 0.0f;
#pragma unroll
      for (int r = 0; r < 4; ++r) {
        const int t = t0 + wm + (i << 4) + (fq << 2) + r;
        float val = acc[i][j][r] + bi;
        const size_t idx = ((size_t)b * T_LEN + t) * (size_t)Mw + co;
        if (HAS_RES) val += bf2f(residB[idx]);
        if (HAS_MASK) val *= mask[(size_t)b * T_LEN + t];
        if (OUT_CT_F32)
          outF[(size_t)b * Mw * T_LEN + (size_t)co * T_LEN + t] = val;
        if (WRITE_BF16) outB[idx] = f2bf(val);
      }
    }
  }
}

// ---------------- launch ---------------------------------------------------
extern "C" void kernel_launch(void* const* d_in, const int* in_sizes, int n_in,
                              void* d_out, int out_size, void* d_ws, size_t ws_size,
                              hipStream_t stream) {
  const float* x    = (const float*)d_in[0];
  const float* mask = (const float*)d_in[1];

  char* ws = (char*)d_ws;
  unsigned short* xT   = (unsigned short*)ws;                 // 67108864 B
  unsigned short* qkv  = xT;                                  // alias (xT dead after gemm0)
  unsigned short* outB = (unsigned short*)(ws + 67108864);    // 16777216 B
  unsigned short* wbuf = (unsigned short*)(ws + 83886080);    // ~3.3 MB (incl. OOB pad)

  const int WB0  = 0;        // 256x1024
  const int WQKV = 262144;   // 5 x 768x256 stacked [wq;wk;wv]
  const int WBT  = 1245184;  // 5 x 256x256
  const int WB6  = 1572864;  // 157x256 (+ pad read up to 256x256)

  WPrepArgs pa;
  int si = 0;
  pa.seg[si++] = { (const float*)d_in[2], 262144, WB0 };
  for (int l = 0; l < 5; ++l) {
    int bi = 4 + l * 5;
    pa.seg[si++] = { (const float*)d_in[bi + 0], 65536, WQKV + l * 196608 };
    pa.seg[si++] = { (const float*)d_in[bi + 1], 65536, WQKV + l * 196608 + 65536 };
    pa.seg[si++] = { (const float*)d_in[bi + 2], 65536, WQKV + l * 196608 + 131072 };
    pa.seg[si++] = { (const float*)d_in[bi + 3], 65536, WBT + l * 65536 };
  }
  pa.seg[si++] = { (const float*)d_in[29], 40192, WB6 };

  wprep_kernel<<<dim3(22, 64), 256, 0, stream>>>(pa, wbuf);
  transpose_xT<<<dim3(64, 16, 8), 256, 0, stream>>>(x, xT);

  // bottle0: out = w0 @ x + b0  (bf16)
  gemm_kernel<false, true, false, false, true, false>
      <<<dim3(2, 32, 8), 256, 0, stream>>>(
          xT, wbuf + WB0, (const float*)d_in[3], nullptr, mask,
          nullptr, outB, 1024, 256, 0);

  const int dils[5] = {1, 2, 4, 8, 16};
  for (int l = 0; l < 5; ++l) {
    int bi = 4 + l * 5;
    // qkv = [wq;wk;wv] @ out  (bf16)
    gemm_kernel<false, false, false, false, true, false>
        <<<dim3(6, 32, 8), 256, 0, stream>>>(
            outB, wbuf + WQKV + l * 196608, nullptr, nullptr, mask,
            nullptr, qkv, 256, 768, 0);
    // out = (out + bw @ relu(attn(qkv)) + bb) * mask   (attn fused in A-staging)
    gemm_kernel<true, true, true, true, true, false>
        <<<dim3(2, 32, 8), 256, 0, stream>>>(
            qkv, wbuf + WBT + l * 65536, (const float*)d_in[bi + 4], outB, mask,
            nullptr, outB, 256, 256, dils[l]);
  }

  // final: d_out(B,157,T) = (w6 @ out + b6) * mask  (channel-major f32 store)
  gemm_kernel<false, true, false, true, false, true>
      <<<dim3(2, 32, 8), 256, 0, stream>>>(
          outB, wbuf + WB6, (const float*)d_in[30], nullptr, mask,
          (float*)d_out, nullptr, 256, 157, 0);
}

// Round 4
// 653.505 us; speedup vs baseline: 1.1110x; 1.0322x over previous
//
#include <hip/hip_runtime.h>
#include <hip/hip_bf16.h>
#include <stdint.h>

#define T_LEN 4096
#define B_SZ  8
#define D_IN  1024
#define D_M   256
#define N_C   157

typedef __attribute__((ext_vector_type(8))) short short8;
typedef __attribute__((ext_vector_type(4))) float floatx4;

static __device__ __forceinline__ unsigned short f2bf(float f) {
  unsigned u = __float_as_uint(f);
  u += 0x7FFFu + ((u >> 16) & 1u);
  return (unsigned short)(u >> 16);
}
static __device__ __forceinline__ float bf2f(unsigned short h) {
  return __uint_as_float(((unsigned)h) << 16);
}

// async global->LDS, 16B per lane; LDS dest = wave-uniform base + lane*16
static __device__ __forceinline__ void gl_lds16(const unsigned short* g,
                                                unsigned short* l) {
  __builtin_amdgcn_global_load_lds(
      (const __attribute__((address_space(1))) unsigned int*)g,
      (__attribute__((address_space(3))) unsigned int*)l, 16, 0, 0);
}

// ---------------- weight prep: fp32 -> bf16, 22 segments ------------------
struct WSeg { const float* src; int n; int off; };
struct WPrepArgs { WSeg seg[22]; };

__global__ void wprep_kernel(WPrepArgs a, unsigned short* __restrict__ wbuf) {
  WSeg s = a.seg[blockIdx.x];
  for (int i = (blockIdx.y << 8) + threadIdx.x; i < s.n; i += (gridDim.y << 8))
    wbuf[s.off + i] = f2bf(s.src[i]);
}

// ---------------- x (B,DIN,T) f32 -> xT (B,T,DIN) bf16 --------------------
__global__ void transpose_xT(const float* __restrict__ x,
                             unsigned short* __restrict__ xT) {
  __shared__ float tile[64][65];
  const int t0 = blockIdx.x << 6;
  const int i0 = blockIdx.y << 6;
  const int b  = blockIdx.z;
  const int tid = threadIdx.x;
  {
    const int row = tid >> 2;
    const int cc  = (tid & 3) << 4;
    const float* src = x + ((size_t)b * D_IN + (i0 + row)) * T_LEN + t0 + cc;
#pragma unroll
    for (int p = 0; p < 4; ++p) {
      float4 v = *(const float4*)(src + p * 4);
      tile[row][cc + p * 4 + 0] = v.x;
      tile[row][cc + p * 4 + 1] = v.y;
      tile[row][cc + p * 4 + 2] = v.z;
      tile[row][cc + p * 4 + 3] = v.w;
    }
  }
  __syncthreads();
#pragma unroll
  for (int it = 0; it < 2; ++it) {
    const int task = tid + (it << 8);
    const int tr = task >> 3;
    const int ic = (task & 7) << 3;
    short8 o;
#pragma unroll
    for (int j = 0; j < 8; ++j) o[j] = (short)f2bf(tile[ic + j][tr]);
    *(short8*)(xT + ((size_t)b * T_LEN + (t0 + tr)) * D_IN + i0 + ic) = o;
  }
}

// ---------------- MFMA GEMM, 64x128 tile, BK=64, dbuf single-barrier ------
// normal: C(B,T,Mw) = A(B,T,K) * W(Mw,K)^T ; sA=act rows(64t), sB=W rows(128n)
// SWAP_CT: C^T store: sA=W rows(64 o), sB=act rows(128 t); out f32 (B,Mw,T)
// LDS swizzle: elem(row,k) at row*64 + ((k/8)^(row&7))*8  (shorts)
// A-frag: A[m=lane&15][k=(lane>>4)*8+j]  B-frag: B[k][n=lane&15]
// C/D: col=lane&15, row=(lane>>4)*4+reg
template<bool ATTN, bool HAS_BIAS, bool HAS_RES, bool HAS_MASK,
         bool WRITE_BF16, bool SWAP_CT>
__global__ __launch_bounds__(256)
void gemm_kernel(const unsigned short* __restrict__ Xact,
                 const unsigned short* __restrict__ W,
                 const float* __restrict__ bias,
                 const unsigned short* __restrict__ residB,
                 const float* __restrict__ mask,
                 float* __restrict__ outF,
                 unsigned short* __restrict__ outB,
                 int K, int Mw, int dil) {
  __shared__ unsigned short sA[2][64 * 64];
  __shared__ unsigned short sB[2][128 * 64];

  const int bx = blockIdx.x;                      // n-block (normal) / o-block (swap)
  const int t0 = blockIdx.y << (SWAP_CT ? 7 : 6); // t rows per block
  const int b  = blockIdx.z;
  const int tid  = threadIdx.x;
  const int wv   = tid >> 6;
  const int lane = tid & 63;
  const int wn   = wv << 5;                       // wave n-offset (32 cols)
  const int fm   = lane & 15;
  const int fq   = lane >> 4;
  const int lrow = lane >> 3;
  const int cbg8 = (((lane & 7) ^ lrow) << 3);

  const unsigned short* Xb =
      Xact + (size_t)b * T_LEN * (size_t)(ATTN ? 768 : K);
  const unsigned short* srcA =
      SWAP_CT ? (W + (size_t)(bx << 6) * K) : (Xb + (size_t)t0 * K);
  const unsigned short* srcB =
      SWAP_CT ? (Xb + (size_t)t0 * K) : (W + (size_t)(bx << 7) * K);

  const short8 z8 = {0, 0, 0, 0, 0, 0, 0, 0};
  const floatx4 fz = {0.f, 0.f, 0.f, 0.f};
  floatx4 acc[4][2];
#pragma unroll
  for (int i = 0; i < 4; ++i)
#pragma unroll
    for (int j = 0; j < 2; ++j) acc[i][j] = fz;

  auto stage = [&](int kk, int bufi) {
    if constexpr (ATTN) {
#pragma unroll
      for (int itp = 0; itp < 2; ++itp) {
        int c = tid + (itp << 8);
        int m = c >> 3;
        int cb = c & 7;
        int ch = kk + (cb << 3);
        int t = t0 + m;
        const unsigned short* base = Xb + (size_t)t * 768 + ch;
        short8 qv = *(const short8*)(base);
        short8 kc = *(const short8*)(base + 256);
        short8 vc = *(const short8*)(base + 512);
        short8 km = z8, kp = z8, vm = z8, vp = z8;
        const long off = (long)dil * 768;
        if (t >= dil) {
          km = *(const short8*)(base - off + 256);
          vm = *(const short8*)(base - off + 512);
        }
        if (t + dil < T_LEN) {
          kp = *(const short8*)(base + off + 256);
          vp = *(const short8*)(base + off + 512);
        }
        short8 o;
#pragma unroll
        for (int e = 0; e < 8; ++e) {
          float q  = bf2f((unsigned short)qv[e]);
          float s0 = q * bf2f((unsigned short)km[e]);
          float s1 = q * bf2f((unsigned short)kc[e]);
          float s2 = q * bf2f((unsigned short)kp[e]);
          float mx = fmaxf(s0, fmaxf(s1, s2));
          float e0 = __expf(s0 - mx), e1 = __expf(s1 - mx), e2 = __expf(s2 - mx);
          float num = e0 * bf2f((unsigned short)vm[e]) +
                      e1 * bf2f((unsigned short)vc[e]) +
                      e2 * bf2f((unsigned short)vp[e]);
          float r = num / (e0 + e1 + e2);
          o[e] = (short)f2bf(fmaxf(r, 0.0f));
        }
        *(short8*)&sA[bufi][(m << 6) + ((cb ^ (m & 7)) << 3)] = o;
      }
    } else {
#pragma unroll
      for (int p = 0; p < 2; ++p) {
        const int slot = (p << 2) + wv;
        gl_lds16(srcA + (size_t)((slot << 3) + lrow) * K + kk + cbg8,
                 &sA[bufi][slot * 512]);
      }
    }
#pragma unroll
    for (int p = 0; p < 4; ++p) {
      const int slot = (p << 2) + wv;
      gl_lds16(srcB + (size_t)((slot << 3) + lrow) * K + kk + cbg8,
               &sB[bufi][slot * 512]);
    }
  };

  const int niter = K >> 6;
  stage(0, 0);
  for (int it = 0; it < niter; ++it) {
    const int p = it & 1;
    __syncthreads();
    if (it + 1 < niter) stage((it + 1) << 6, 1 - p);
#pragma unroll
    for (int ks = 0; ks < 64; ks += 32) {
      const int cbase = ((fq + (ks >> 3)) ^ (fm & 7)) << 3;
      short8 af[4], bfr[2];
#pragma unroll
      for (int i = 0; i < 4; ++i)
        af[i] = *(short8*)&sA[p][(((i << 4) + fm) << 6) + cbase];
#pragma unroll
      for (int j = 0; j < 2; ++j)
        bfr[j] = *(short8*)&sB[p][((wn + (j << 4) + fm) << 6) + cbase];
#pragma unroll
      for (int i = 0; i < 4; ++i)
#pragma unroll
        for (int j = 0; j < 2; ++j)
          acc[i][j] = __builtin_amdgcn_mfma_f32_16x16x32_bf16(
              af[i], bfr[j], acc[i][j], 0, 0, 0);
    }
  }

  // epilogue
  if constexpr (SWAP_CT) {
#pragma unroll
    for (int i = 0; i < 4; ++i) {
#pragma unroll
      for (int r = 0; r < 4; ++r) {
        const int o = (bx << 6) + (i << 4) + (fq << 2) + r;
        if (o >= Mw) continue;
        const float bi = HAS_BIAS ? bias[o] : 0.0f;
#pragma unroll
        for (int j = 0; j < 2; ++j) {
          const int t = t0 + wn + (j << 4) + fm;
          float val = acc[i][j][r] + bi;
          if (HAS_MASK) val *= mask[(size_t)b * T_LEN + t];
          outF[((size_t)b * Mw + o) * T_LEN + t] = val;
        }
      }
    }
  } else {
#pragma unroll
    for (int i = 0; i < 4; ++i) {
#pragma unroll
      for (int j = 0; j < 2; ++j) {
        const int co = (bx << 7) + wn + (j << 4) + fm;
        if (co >= Mw) continue;
        const float bi = HAS_BIAS ? bias[co] : 0.0f;
#pragma unroll
        for (int r = 0; r < 4; ++r) {
          const int t = t0 + (i << 4) + (fq << 2) + r;
          float val = acc[i][j][r] + bi;
          const size_t idx = ((size_t)b * T_LEN + t) * (size_t)Mw + co;
          if (HAS_RES) val += bf2f(residB[idx]);
          if (HAS_MASK) val *= mask[(size_t)b * T_LEN + t];
          if (WRITE_BF16) outB[idx] = f2bf(val);
        }
      }
    }
  }
}

// ---------------- launch ---------------------------------------------------
extern "C" void kernel_launch(void* const* d_in, const int* in_sizes, int n_in,
                              void* d_out, int out_size, void* d_ws, size_t ws_size,
                              hipStream_t stream) {
  const float* x    = (const float*)d_in[0];
  const float* mask = (const float*)d_in[1];

  char* ws = (char*)d_ws;
  unsigned short* xT   = (unsigned short*)ws;                 // 67108864 B
  unsigned short* qkv  = xT;                                  // alias (xT dead after gemm0)
  unsigned short* outB = (unsigned short*)(ws + 67108864);    // 16777216 B
  unsigned short* wbuf = (unsigned short*)(ws + 83886080);    // ~3.3 MB (incl. OOB pad)

  const int WB0  = 0;        // 256x1024
  const int WQKV = 262144;   // 5 x 768x256 stacked [wq;wk;wv]
  const int WBT  = 1245184;  // 5 x 256x256
  const int WB6  = 1572864;  // 157x256 (+ pad read up to 192x256)

  WPrepArgs pa;
  int si = 0;
  pa.seg[si++] = { (const float*)d_in[2], 262144, WB0 };
  for (int l = 0; l < 5; ++l) {
    int bi = 4 + l * 5;
    pa.seg[si++] = { (const float*)d_in[bi + 0], 65536, WQKV + l * 196608 };
    pa.seg[si++] = { (const float*)d_in[bi + 1], 65536, WQKV + l * 196608 + 65536 };
    pa.seg[si++] = { (const float*)d_in[bi + 2], 65536, WQKV + l * 196608 + 131072 };
    pa.seg[si++] = { (const float*)d_in[bi + 3], 65536, WBT + l * 65536 };
  }
  pa.seg[si++] = { (const float*)d_in[29], 40192, WB6 };

  wprep_kernel<<<dim3(22, 64), 256, 0, stream>>>(pa, wbuf);
  transpose_xT<<<dim3(64, 16, 8), 256, 0, stream>>>(x, xT);

  // bottle0: out = w0 @ x + b0  (bf16)
  gemm_kernel<false, true, false, false, true, false>
      <<<dim3(2, 64, 8), 256, 0, stream>>>(
          xT, wbuf + WB0, (const float*)d_in[3], nullptr, mask,
          nullptr, outB, 1024, 256, 0);

  const int dils[5] = {1, 2, 4, 8, 16};
  for (int l = 0; l < 5; ++l) {
    int bi = 4 + l * 5;
    // qkv = [wq;wk;wv] @ out  (bf16)
    gemm_kernel<false, false, false, false, true, false>
        <<<dim3(6, 64, 8), 256, 0, stream>>>(
            outB, wbuf + WQKV + l * 196608, nullptr, nullptr, mask,
            nullptr, qkv, 256, 768, 0);
    // out = (out + bw @ relu(attn(qkv)) + bb) * mask  (attn fused in A-staging)
    gemm_kernel<true, true, true, true, true, false>
        <<<dim3(2, 64, 8), 256, 0, stream>>>(
            qkv, wbuf + WBT + l * 65536, (const float*)d_in[bi + 4], outB, mask,
            nullptr, outB, 256, 256, dils[l]);
  }

  // final: d_out(B,157,T) = (w6 @ out + b6) * mask  (swapped operands:
  // C rows=o, cols=t -> contiguous f32 channel-major stores)
  gemm_kernel<false, true, false, true, false, true>
      <<<dim3(3, 32, 8), 256, 0, stream>>>(
          outB, wbuf + WB6, (const float*)d_in[30], nullptr, mask,
          (float*)d_out, nullptr, 256, 157, 0);
}